// Round 1
// baseline (55.396 us; speedup 1.0000x reference)
//
#include <hip/hip_runtime.h>

// TransformerBlockQuantum: B=16384, S=8, E=8, H=8 (dk=1), NW=8, FFN=512.
// Fully fused: one thread per token (batch,s); 8 lanes = 1 batch.
// Cross-token attention exchange via ds_swizzle 8-lane broadcast.
// All weights accessed wave-uniformly -> scalar loads (s_load), K$-cached.

#define SWZ(v, J) __int_as_float(__builtin_amdgcn_ds_swizzle(__float_as_int(v), ((J) << 5) | 0x18))

__global__ __launch_bounds__(256) void tbq_fused(
    const float* __restrict__ x,
    const float* __restrict__ ipw, const float* __restrict__ ipb,
    const float* __restrict__ opw, const float* __restrict__ opb,
    const float* __restrict__ rxa,
    const float* __restrict__ cw,  const float* __restrict__ cb,
    const float* __restrict__ g1,  const float* __restrict__ b1,
    const float* __restrict__ rxf,
    const float* __restrict__ l1w, const float* __restrict__ l1b,
    const float* __restrict__ l2w, const float* __restrict__ l2b,
    const float* __restrict__ g2,  const float* __restrict__ b2,
    float* __restrict__ out)
{
    const int tid  = blockIdx.x * 256 + threadIdx.x;   // token id = b*8 + s
    const int base = tid * 8;

    // ---- load own x row (coalesced, 32B/lane) ----
    float xr[8];
    {
        const float4* px = reinterpret_cast<const float4*>(x + base);
        float4 a = px[0], b = px[1];
        xr[0] = a.x; xr[1] = a.y; xr[2] = a.z; xr[3] = a.w;
        xr[4] = b.x; xr[5] = b.y; xr[6] = b.z; xr[7] = b.w;
    }

    // ---- in_proj: q,k,v for own token ----
    float q[8], k[8], v[8];
    #pragma unroll
    for (int e = 0; e < 8; ++e) {
        float aq = ipb[e], ak = ipb[8 + e], av = ipb[16 + e];
        #pragma unroll
        for (int d = 0; d < 8; ++d) {
            aq = fmaf(xr[d], ipw[e * 8 + d],       aq);
            ak = fmaf(xr[d], ipw[64 + e * 8 + d],  ak);
            av = fmaf(xr[d], ipw[128 + e * 8 + d], av);
        }
        q[e] = aq; k[e] = ak; v[e] = av;
    }

    // ---- attention per head (dk=1, scale=1): softmax_j(q_h[i]*k_h[j]) @ v_h ----
    float orow[8];
    #pragma unroll
    for (int h = 0; h < 8; ++h) {
        const float kh = k[h], vh = v[h], qh = q[h];
        float kk[8], vv[8];
        kk[0] = SWZ(kh, 0); kk[1] = SWZ(kh, 1); kk[2] = SWZ(kh, 2); kk[3] = SWZ(kh, 3);
        kk[4] = SWZ(kh, 4); kk[5] = SWZ(kh, 5); kk[6] = SWZ(kh, 6); kk[7] = SWZ(kh, 7);
        vv[0] = SWZ(vh, 0); vv[1] = SWZ(vh, 1); vv[2] = SWZ(vh, 2); vv[3] = SWZ(vh, 3);
        vv[4] = SWZ(vh, 4); vv[5] = SWZ(vh, 5); vv[6] = SWZ(vh, 6); vv[7] = SWZ(vh, 7);
        float sc[8];
        #pragma unroll
        for (int j = 0; j < 8; ++j) sc[j] = qh * kk[j];
        float m = fmaxf(fmaxf(fmaxf(sc[0], sc[1]), fmaxf(sc[2], sc[3])),
                        fmaxf(fmaxf(sc[4], sc[5]), fmaxf(sc[6], sc[7])));
        float p[8];
        #pragma unroll
        for (int j = 0; j < 8; ++j) p[j] = __expf(sc[j] - m);
        float sum = ((p[0] + p[1]) + (p[2] + p[3])) + ((p[4] + p[5]) + (p[6] + p[7]));
        float ov = 0.f;
        #pragma unroll
        for (int j = 0; j < 8; ++j) ov = fmaf(p[j], vv[j], ov);
        orow[h] = ov * __builtin_amdgcn_rcpf(sum);
    }

    // ---- out_proj ----
    float ao[8];
    #pragma unroll
    for (int e = 0; e < 8; ++e) {
        float t = opb[e];
        #pragma unroll
        for (int h = 0; h < 8; ++h) t = fmaf(orow[h], opw[e * 8 + h], t);
        ao[e] = t;
    }

    // ---- quantum circuit: cos(theta), CNOT-ring Z expectations ----
    float c[8];
    #pragma unroll
    for (int w = 0; w < 8; ++w) c[w] = __cosf(ao[w] + rxa[w]);
    float z[8];
    {
        float run = c[0];
        #pragma unroll
        for (int w = 1; w < 8; ++w) { run *= c[w]; z[w] = run; }   // cumprod
        float s17 = c[1];
        #pragma unroll
        for (int w = 2; w < 8; ++w) s17 *= c[w];                    // prod c[1:]
        z[0] = s17;
    }

    // ---- q_out = z@Cw^T + cb ; attn_total = (ao + q_out)@Cw^T + cb ----
    float saq[8];
    #pragma unroll
    for (int e = 0; e < 8; ++e) {
        float t = cb[e];
        #pragma unroll
        for (int w = 0; w < 8; ++w) t = fmaf(z[w], cw[e * 8 + w], t);
        saq[e] = ao[e] + t;
    }
    float at[8];
    #pragma unroll
    for (int e = 0; e < 8; ++e) {
        float t = cb[e];
        #pragma unroll
        for (int w = 0; w < 8; ++w) t = fmaf(saq[w], cw[e * 8 + w], t);
        at[e] = t;
    }

    // ---- LayerNorm1(x + attn_total) ----
    float hh[8];
    {
        float r[8]; float mean = 0.f;
        #pragma unroll
        for (int e = 0; e < 8; ++e) { r[e] = xr[e] + at[e]; mean += r[e]; }
        mean *= 0.125f;
        float var = 0.f;
        #pragma unroll
        for (int e = 0; e < 8; ++e) { float d = r[e] - mean; var = fmaf(d, d, var); }
        var *= 0.125f;
        float rs = __builtin_amdgcn_rsqf(var + 1e-5f);
        #pragma unroll
        for (int e = 0; e < 8; ++e) hh[e] = fmaf((r[e] - mean) * rs, g1[e], b1[e]);
    }

    // ---- quantum FFN: zf = cos(h + rx_ffn); relu(zf@W1^T+b1)@W2^T+b2 ----
    float zf[8];
    #pragma unroll
    for (int w = 0; w < 8; ++w) zf[w] = __cosf(hh[w] + rxf[w]);

    float acc[8];
    #pragma unroll
    for (int e = 0; e < 8; ++e) acc[e] = l2b[e];

    #pragma unroll 2
    for (int f = 0; f < 512; f += 2) {
        float u0 = l1b[f], u1 = l1b[f + 1];
        #pragma unroll
        for (int w = 0; w < 8; ++w) {
            u0 = fmaf(zf[w], l1w[f * 8 + w],     u0);
            u1 = fmaf(zf[w], l1w[f * 8 + 8 + w], u1);
        }
        u0 = fmaxf(u0, 0.f); u1 = fmaxf(u1, 0.f);
        #pragma unroll
        for (int e = 0; e < 8; ++e) {
            acc[e] = fmaf(u1, l2w[e * 512 + f + 1], fmaf(u0, l2w[e * 512 + f], acc[e]));
        }
    }

    // ---- LayerNorm2(h + ffn_out) + store ----
    float r2[8]; float mean2 = 0.f;
    #pragma unroll
    for (int e = 0; e < 8; ++e) { r2[e] = hh[e] + acc[e]; mean2 += r2[e]; }
    mean2 *= 0.125f;
    float var2 = 0.f;
    #pragma unroll
    for (int e = 0; e < 8; ++e) { float d = r2[e] - mean2; var2 = fmaf(d, d, var2); }
    var2 *= 0.125f;
    float rs2 = __builtin_amdgcn_rsqf(var2 + 1e-5f);
    float o[8];
    #pragma unroll
    for (int e = 0; e < 8; ++e) o[e] = fmaf((r2[e] - mean2) * rs2, g2[e], b2[e]);

    float4* po = reinterpret_cast<float4*>(out + base);
    po[0] = make_float4(o[0], o[1], o[2], o[3]);
    po[1] = make_float4(o[4], o[5], o[6], o[7]);
}

extern "C" void kernel_launch(void* const* d_in, const int* in_sizes, int n_in,
                              void* d_out, int out_size, void* d_ws, size_t ws_size,
                              hipStream_t stream) {
    const float* x   = (const float*)d_in[0];
    const float* ipw = (const float*)d_in[1];
    const float* ipb = (const float*)d_in[2];
    const float* opw = (const float*)d_in[3];
    const float* opb = (const float*)d_in[4];
    const float* rxa = (const float*)d_in[5];
    const float* cw  = (const float*)d_in[6];
    const float* cb  = (const float*)d_in[7];
    const float* g1  = (const float*)d_in[8];
    const float* b1  = (const float*)d_in[9];
    const float* rxf = (const float*)d_in[10];
    const float* l1w = (const float*)d_in[11];
    const float* l1b = (const float*)d_in[12];
    const float* l2w = (const float*)d_in[13];
    const float* l2b = (const float*)d_in[14];
    const float* g2  = (const float*)d_in[15];
    const float* b2  = (const float*)d_in[16];
    float* out = (float*)d_out;

    const int tokens = 16384 * 8;           // 131072 tokens
    tbq_fused<<<dim3(tokens / 256), dim3(256), 0, stream>>>(
        x, ipw, ipb, opw, opb, rxa, cw, cb, g1, b1, rxf,
        l1w, l1b, l2w, l2b, g2, b2, out);
}